// Round 11
// baseline (251.612 us; speedup 1.0000x reference)
//
#include <hip/hip_runtime.h>

#define BB 32
#define LL 2048
#define DD 128
// Q pre-scale: (1/sqrt(128)) * log2(e)  -> MFMA scores land in log2 units
#define SCALE2 0.12753102f
#define DELTA2 0.0173123f     // 0.012 * log2(e)
#define CAPA 4096

typedef _Float16 half8 __attribute__((ext_vector_type(8)));
typedef float f4 __attribute__((ext_vector_type(4)));

struct __align__(32) RB { unsigned grow, i1, i2; float p1, p2; unsigned pad[3]; };

#define CVT8(h_, x_, y_) do {                                               \
    h_[0]=(_Float16)x_[0]; h_[1]=(_Float16)x_[1];                           \
    h_[2]=(_Float16)x_[2]; h_[3]=(_Float16)x_[3];                           \
    h_[4]=(_Float16)y_[0]; h_[5]=(_Float16)y_[1];                           \
    h_[6]=(_Float16)y_[2]; h_[7]=(_Float16)y_[3];                           \
} while (0)

// Branch-free top-3, packed indices (i1<<16 | i2), absolute exp2 accumulation.
#define TOP3(u_, s_, key_) do {                                             \
    const bool c1_ = (s_) > m1[u_];                                         \
    const bool c2_ = (s_) > m2[u_];                                         \
    const unsigned p_ = ip[u_];                                             \
    const unsigned cnd1_ = ((unsigned)(key_) << 16) | (p_ >> 16);           \
    const unsigned cnd2_ = (p_ & 0xFFFF0000u) | (unsigned)(key_);           \
    ip[u_] = c1_ ? cnd1_ : (c2_ ? cnd2_ : p_);                              \
    m3[u_] = __builtin_amdgcn_fmed3f(s_, m2[u_], m3[u_]);                   \
    m2[u_] = __builtin_amdgcn_fmed3f(s_, m1[u_], m2[u_]);                   \
    m1[u_] = fmaxf(s_, m1[u_]);                                             \
    sm[u_] += __builtin_amdgcn_exp2f(s_);                                   \
} while (0)

// staging write: logical (quarter q_, sub jj_) of row with rm_=row&15,
// stored at 16B slot ((4q+jj)^rm) -> exact 4-way (b128 floor) on reads+writes
#define STG_WR(wb_, q_, jj_, rm_, h_)                                       \
    *(half8*)((wb_) + ((((q_) << 2) + (jj_)) ^ (rm_)) * 16) = h_

// compute one 16-key subtile from LDS
#define SUBTILE(s_) do {                                                    \
    const char* rowp = rbuf + (((s_) << 4) + col) * 256;                    \
    half8 bf0 = *(const half8*)(rowp + (((0 << 2) + kg) ^ col) * 16);       \
    half8 bf1 = *(const half8*)(rowp + (((1 << 2) + kg) ^ col) * 16);       \
    half8 bf2 = *(const half8*)(rowp + (((2 << 2) + kg) ^ col) * 16);       \
    half8 bf3 = *(const half8*)(rowp + (((3 << 2) + kg) ^ col) * 16);       \
    f4 acc = {0.f, 0.f, 0.f, 0.f};                                          \
    acc = __builtin_amdgcn_mfma_f32_16x16x32_f16(qa[0], bf0, acc, 0, 0, 0); \
    acc = __builtin_amdgcn_mfma_f32_16x16x32_f16(qa[1], bf1, acc, 0, 0, 0); \
    acc = __builtin_amdgcn_mfma_f32_16x16x32_f16(qa[2], bf2, acc, 0, 0, 0); \
    acc = __builtin_amdgcn_mfma_f32_16x16x32_f16(qa[3], bf3, acc, 0, 0, 0); \
    const int key = (kt << 7) + ((s_) << 4) + col;                          \
    _Pragma("unroll")                                                       \
    for (int j = 0; j < 4; ++j) { float sc = acc[j]; TOP3(j, sc, key); }    \
} while (0)

// ---- main kernel: 1024 blocks (QB=64), BK=128 K-tiles in LDS (2 x 32 KB),
// ---- 4-bit XOR swizzle (4-way = b128 floor), 16 barriers, pulse staging,
// ---- fire-and-forget NT zeroing of the attn plane (lgkmcnt-only barrier).
__global__ __launch_bounds__(256, 2)
void attn_main(const float* __restrict__ Q, const float* __restrict__ K,
               const float* __restrict__ V, float* __restrict__ out,
               int2* __restrict__ recs,
               unsigned* __restrict__ cntA, unsigned* __restrict__ cntB,
               uint2* __restrict__ listA, RB* __restrict__ listB, int capB)
{
    const int P    = blockIdx.x;
    const int x    = P & 7;                 // XCD (round-robin dispatch)
    const int mm   = P >> 3;                // 0..127
    const int b    = (x << 2) + (mm >> 5);  // XCD x owns batches 4x..4x+3
    const int q0   = (mm & 31) << 6;        // 64-row q-tile
    const int tid  = threadIdx.x;
    const int wv   = tid >> 6;
    const int lane = tid & 63;
    const int col  = lane & 15;
    const int kg   = lane >> 4;
    const int wq0  = q0 + (wv << 4);        // wave's 16 q-rows

    const float* kbat = K + (size_t)b * LL * DD;
    float* plane = out + (size_t)BB * LL * DD;
    f4* zb = (f4*)(plane + ((size_t)(b * LL + q0)) * LL);   // 32768 f4 to zero

    __shared__ __align__(16) _Float16 Klds[2][128][128];    // 2 x 32 KB

    // Q A-fragments pre-scaled by SCALE2: lane holds Q[wq0+col][db*32+kg*8+j]
    half8 qa[4];
    {
        const float* qsrc = Q + ((size_t)b * LL + wq0 + col) * DD + (kg << 3);
#pragma unroll
        for (int db = 0; db < 4; ++db) {
            f4 xx = *(const f4*)(qsrc + db * 32);
            f4 yy = *(const f4*)(qsrc + db * 32 + 4);
            half8 h;
            h[0]=(_Float16)(xx[0]*SCALE2); h[1]=(_Float16)(xx[1]*SCALE2);
            h[2]=(_Float16)(xx[2]*SCALE2); h[3]=(_Float16)(xx[3]*SCALE2);
            h[4]=(_Float16)(yy[0]*SCALE2); h[5]=(_Float16)(yy[1]*SCALE2);
            h[6]=(_Float16)(yy[2]*SCALE2); h[7]=(_Float16)(yy[3]*SCALE2);
            qa[db] = h;
        }
    }

    float m1[4], m2[4], m3[4], sm[4];
    unsigned ip[4];
#pragma unroll
    for (int u = 0; u < 4; ++u) { m1[u]=m2[u]=m3[u]=-1e30f; sm[u]=0.f; ip[u]=0u; }

    const int r   = tid >> 2;          // staging row 0..63 (phase 0; +64 phase 1)
    const int q   = tid & 3;           // staging quarter (32 floats)
    const int rm  = r & 15;            // write-side swizzle key (==row&15 both phases)
    char* lb0 = (char*)&Klds[0][0][0];
    char* lb1 = (char*)&Klds[1][0][0];
    const float* srow = kbat + (size_t)r * DD + (q << 5);   // phase-0 source

    // prologue: stage tile 0 -> LDS[0] (both phases, pulsed)
    {
        char* wb = lb0 + r * 256;
        f4 a0,a1,a2,a3; half8 h;
        a0 = *(const f4*)(srow);      a1 = *(const f4*)(srow + 4);
        a2 = *(const f4*)(srow + 8);  a3 = *(const f4*)(srow + 12);
        CVT8(h, a0, a1); STG_WR(wb, q, 0, rm, h);
        CVT8(h, a2, a3); STG_WR(wb, q, 1, rm, h);
        a0 = *(const f4*)(srow + 16); a1 = *(const f4*)(srow + 20);
        a2 = *(const f4*)(srow + 24); a3 = *(const f4*)(srow + 28);
        CVT8(h, a0, a1); STG_WR(wb, q, 2, rm, h);
        CVT8(h, a2, a3); STG_WR(wb, q, 3, rm, h);
        const float* s2 = srow + 64 * DD;
        char* wb2 = lb0 + (64 + r) * 256;
        a0 = *(const f4*)(s2);      a1 = *(const f4*)(s2 + 4);
        a2 = *(const f4*)(s2 + 8);  a3 = *(const f4*)(s2 + 12);
        CVT8(h, a0, a1); STG_WR(wb2, q, 0, rm, h);
        CVT8(h, a2, a3); STG_WR(wb2, q, 1, rm, h);
        a0 = *(const f4*)(s2 + 16); a1 = *(const f4*)(s2 + 20);
        a2 = *(const f4*)(s2 + 24); a3 = *(const f4*)(s2 + 28);
        CVT8(h, a0, a1); STG_WR(wb2, q, 2, rm, h);
        CVT8(h, a2, a3); STG_WR(wb2, q, 3, rm, h);
    }
    __syncthreads();

    for (int kt = 0; kt < 16; ++kt) {
        char* rbuf = (kt & 1) ? lb1 : lb0;
        char* wbuf = (kt & 1) ? lb0 : lb1;
        const float* sA = srow + (size_t)(kt + 1) * 128 * DD;   // phase-0 src
        const float* sC = sA + 64 * DD;                         // phase-1 src
        char* wbA = wbuf + r * 256;
        char* wbC = wbuf + (64 + r) * 256;
        f4 a0, a1, a2, a3;
        half8 h;
        const bool st = (kt < 15);
        f4 z = {0.f,0.f,0.f,0.f};
        f4* zd = zb + (size_t)kt * 2048 + tid;

        if (st) {   // pulse A issue
            a0 = *(const f4*)(sA);      a1 = *(const f4*)(sA + 4);
            a2 = *(const f4*)(sA + 8);  a3 = *(const f4*)(sA + 12);
        }
        SUBTILE(0); SUBTILE(1);
        if (st) {   // write A; issue B
            CVT8(h, a0, a1); STG_WR(wbA, q, 0, rm, h);
            CVT8(h, a2, a3); STG_WR(wbA, q, 1, rm, h);
            a0 = *(const f4*)(sA + 16); a1 = *(const f4*)(sA + 20);
            a2 = *(const f4*)(sA + 24); a3 = *(const f4*)(sA + 28);
        }
        __builtin_nontemporal_store(z, zd);
        __builtin_nontemporal_store(z, zd + 256);
        SUBTILE(2); SUBTILE(3);
        if (st) {   // write B; issue C
            CVT8(h, a0, a1); STG_WR(wbA, q, 2, rm, h);
            CVT8(h, a2, a3); STG_WR(wbA, q, 3, rm, h);
            a0 = *(const f4*)(sC);      a1 = *(const f4*)(sC + 4);
            a2 = *(const f4*)(sC + 8);  a3 = *(const f4*)(sC + 12);
        }
        __builtin_nontemporal_store(z, zd + 512);
        __builtin_nontemporal_store(z, zd + 768);
        SUBTILE(4); SUBTILE(5);
        if (st) {   // write C; issue D
            CVT8(h, a0, a1); STG_WR(wbC, q, 0, rm, h);
            CVT8(h, a2, a3); STG_WR(wbC, q, 1, rm, h);
            a0 = *(const f4*)(sC + 16); a1 = *(const f4*)(sC + 20);
            a2 = *(const f4*)(sC + 24); a3 = *(const f4*)(sC + 28);
        }
        __builtin_nontemporal_store(z, zd + 1024);
        __builtin_nontemporal_store(z, zd + 1280);
        SUBTILE(6); SUBTILE(7);
        if (st) {   // write D
            CVT8(h, a0, a1); STG_WR(wbC, q, 2, rm, h);
            CVT8(h, a2, a3); STG_WR(wbC, q, 3, rm, h);
        }
        __builtin_nontemporal_store(z, zd + 1536);
        __builtin_nontemporal_store(z, zd + 1792);

        // raw barrier: waits LDS ops only; global stores stay in flight
        asm volatile("s_waitcnt lgkmcnt(0)" ::: "memory");
        __builtin_amdgcn_s_barrier();
    }

    // butterfly merge across the 16 column-lanes (sm merges by simple add)
#pragma unroll
    for (int off = 1; off < 16; off <<= 1) {
#pragma unroll
        for (int u = 0; u < 4; ++u) {
            float om1 = __shfl_xor(m1[u], off);
            float om2 = __shfl_xor(m2[u], off);
            float om3 = __shfl_xor(m3[u], off);
            float osm = __shfl_xor(sm[u], off);
            unsigned oip = __shfl_xor((int)ip[u], off);
            sm[u] += osm;
            if (om1 > m1[u]) {
                float t2; unsigned tp;
                t2=m1[u]; m1[u]=om1; om1=t2;
                t2=m2[u]; m2[u]=om2; om2=t2;
                t2=m3[u]; m3[u]=om3; om3=t2;
                tp=ip[u]; ip[u]=oip; oip=tp;
            }
            if (om1 > m2[u]) { m3[u]=fmaxf(m2[u], om2); m2[u]=om1;
                               ip[u]=(ip[u]&0xFFFF0000u)|(oip>>16); }
            else             { m3[u]=fmaxf(m3[u], om1); }
        }
    }

    if (col == 0) {
#pragma unroll
        for (int u = 0; u < 4; ++u) {
            const int grow = b * LL + wq0 + (kg << 2) + u;
            const unsigned i1u = ip[u] >> 16, i2u = ip[u] & 0xFFFFu;
            float p1 = __builtin_amdgcn_exp2f(m1[u]) / sm[u];
            float g13 = m1[u] - m3[u];
            float g12 = m1[u] - m2[u];
            unsigned flag = 0u;
            if (g13 <= DELTA2) {
                flag = 0x80000000u;
                unsigned slotA = atomicAdd(cntA, 1u);
                if (slotA < CAPA) listA[slotA] = make_uint2((unsigned)grow, i1u);
            } else if (g12 <= DELTA2) {
                flag = 0x80000000u;
                unsigned slotB = atomicAdd(cntB, 1u);
                if (slotB < (unsigned)capB) {
                    RB rb; rb.grow=(unsigned)grow; rb.i1=i1u; rb.i2=i2u;
                    rb.p1=p1; rb.p2=__builtin_amdgcn_exp2f(m2[u])/sm[u];
                    rb.pad[0]=rb.pad[1]=rb.pad[2]=0;
                    listB[slotB] = rb;
                }
            }
            recs[grow] = make_int2((int)(i1u | flag), __float_as_int(p1));
        }
    }

    // output rows: all lanes hold merged state; lane writes 32B of row kg*4+u
#pragma unroll
    for (int u = 0; u < 4; ++u) {
        const int grow = b * LL + wq0 + (kg << 2) + u;
        float p1 = __builtin_amdgcn_exp2f(m1[u]) / sm[u];
        const float* vs = V + ((size_t)b * LL + (ip[u] >> 16)) * DD + (col << 3);
        float* dst = out + (size_t)grow * DD + (col << 3);
        f4 v0 = *(const f4*)(vs);
        f4 v1 = *(const f4*)(vs + 4);
        *(f4*)(dst)     = v0 * p1;
        *(f4*)(dst + 4) = v1 * p1;
    }
}

// ---- merged epilogue: scatter p (skip flagged rows) + fp64 fix-ups.
// ---- All roles touch disjoint rows -> safe in one concurrent kernel.
__global__ __launch_bounds__(256)
void epilogue(const float* __restrict__ Q, const float* __restrict__ K,
              const float* __restrict__ V, float* __restrict__ out,
              const int2* __restrict__ recs,
              const unsigned* __restrict__ cntA, const unsigned* __restrict__ cntB,
              const uint2* __restrict__ listA, const RB* __restrict__ listB, int capB)
{
    __shared__ float  qsh[DD];
    __shared__ double rbuf[256];
    __shared__ int    ibuf[256];
    float* plane = out + (size_t)BB * LL * DD;
    const int bid = blockIdx.x;
    const int tid = threadIdx.x;

    if (bid < 256) {
        // ---- scatter role: place p at argmax for unflagged rows ----
        const int grow = bid * 256 + tid;
        int2 rr = recs[grow];
        if (rr.x >= 0)
            plane[(size_t)grow * LL + rr.x] = __int_as_float(rr.y);
        return;
    }

    if (bid < 320) {
        // ---- fix-full role: fp64 full-row rescan for listA entries ----
        int n = (int)min(*cntA, (unsigned)CAPA);
        for (int e = bid - 256; e < n; e += 64) {
            uint2 en = listA[e];
            int grow = (int)en.x;
            int b = grow >> 11;
            __syncthreads();
            if (tid < DD) qsh[tid] = Q[(size_t)grow * DD + tid];
            __syncthreads();
            double ls[8];
            double best = -1e300; int bidx = 0;
#pragma unroll
            for (int kk = 0; kk < 8; ++kk) {
                int key = (kk << 8) + tid;
                const float* kr = K + ((size_t)(b << 11) + key) * DD;
                double acc = 0.0;
                for (int d = 0; d < DD; ++d) acc += (double)qsh[d] * (double)kr[d];
                acc *= (double)0.08838834764831845;
                ls[kk] = acc;
                if (acc > best) { best = acc; bidx = key; }
            }
            rbuf[tid] = best; ibuf[tid] = bidx;
            __syncthreads();
            for (int s2 = 128; s2 > 0; s2 >>= 1) {
                if (tid < s2 && rbuf[tid + s2] > rbuf[tid]) { rbuf[tid]=rbuf[tid+s2]; ibuf[tid]=ibuf[tid+s2]; }
                __syncthreads();
            }
            double gbest = rbuf[0]; int gidx = ibuf[0];
            __syncthreads();
            double lsum = 0.0;
#pragma unroll
            for (int kk = 0; kk < 8; ++kk) lsum += exp(ls[kk] - gbest);
            rbuf[tid] = lsum;
            __syncthreads();
            for (int s2 = 128; s2 > 0; s2 >>= 1) {
                if (tid < s2) rbuf[tid] += rbuf[tid + s2];
                __syncthreads();
            }
            float p = (float)(1.0 / rbuf[0]);
            if (tid == 0) plane[(size_t)grow * LL + gidx] = p;   // row was left zeroed
            if (tid < DD) out[(size_t)grow * DD + tid] = p * V[((size_t)(b << 11) + gidx) * DD + tid];
            __syncthreads();
        }
        return;
    }

    // ---- fix-pair role: fp64 two-candidate compare, 4 waves/block ----
    {
        int n = (int)min(*cntB, (unsigned)capB);
        const int lane = tid & 63;
        for (int e = (bid - 320) * 4 + (tid >> 6); e < n; e += 256) {
            RB r = listB[e];
            int b = (int)(r.grow >> 11);
            const float* qq = Q + (size_t)r.grow * DD;
            const float* k1 = K + ((size_t)(b << 11) + r.i1) * DD;
            const float* k2 = K + ((size_t)(b << 11) + r.i2) * DD;
            double a1 = 0.0, a2 = 0.0;
            for (int d = lane; d < DD; d += 64) {
                double qd = (double)qq[d];
                a1 += qd * (double)k1[d];
                a2 += qd * (double)k2[d];
            }
#pragma unroll
            for (int off = 32; off > 0; off >>= 1) {
                a1 += __shfl_down(a1, off);
                a2 += __shfl_down(a2, off);
            }
            int sel = (a2 > a1) ? 1 : 0;
            sel = __shfl(sel, 0);
            const unsigned widx = sel ? r.i2 : r.i1;
            const float    wp   = sel ? r.p2 : r.p1;
            if (lane == 0)
                plane[(size_t)r.grow * LL + widx] = wp;   // row was left zeroed
            if (sel) {
                const float* vs = V + ((size_t)(b << 11) + r.i2) * DD;
                float* dst = out + (size_t)r.grow * DD;
                for (int d = lane; d < DD; d += 64) dst[d] = r.p2 * vs[d];
            }
        }
    }
}

extern "C" void kernel_launch(void* const* d_in, const int* in_sizes, int n_in,
                              void* d_out, int out_size, void* d_ws, size_t ws_size,
                              hipStream_t stream)
{
    const float* Q = (const float*)d_in[0];
    const float* K = (const float*)d_in[1];
    const float* V = (const float*)d_in[2];
    float* out = (float*)d_out;

    // ws layout: [0,8) counters | [64, 64+512K) records | listA | listB
    unsigned* cntA = (unsigned*)d_ws;
    unsigned* cntB = cntA + 1;
    int2* recs = (int2*)((char*)d_ws + 64);
    size_t offA = 64 + (size_t)BB * LL * 8;              // 524352
    uint2* listA = (uint2*)((char*)d_ws + offA);
    size_t offB = offA + (size_t)CAPA * 8;               // 557120, 32B-aligned
    RB* listB = (RB*)((char*)d_ws + offB);
    int capB = 0;
    if (ws_size > offB + 32) capB = (int)((ws_size - offB) / 32);
    if (capB > 65536) capB = 65536;

    hipMemsetAsync(d_ws, 0, 8, stream);                  // zero both counters
    hipLaunchKernelGGL(attn_main, dim3(1024), dim3(256), 0, stream,
                       Q, K, V, out, recs, cntA, cntB, listA, listB, capB);
    hipLaunchKernelGGL(epilogue, dim3(384), dim3(256), 0, stream,
                       Q, K, V, out, recs, cntA, cntB, listA, listB, capB);
}

// Round 13
// 244.768 us; speedup vs baseline: 1.0280x; 1.0280x over previous
//
#include <hip/hip_runtime.h>

#define BB 32
#define LL 2048
#define DD 128
// Q pre-scale: (1/sqrt(128)) * log2(e)  -> MFMA scores land in log2 units
#define SCALE2 0.12753102f
#define DELTA2 0.0173123f     // 0.012 * log2(e)
#define CAPA 4096

typedef _Float16 half8 __attribute__((ext_vector_type(8)));
typedef __fp16 h2 __attribute__((ext_vector_type(2)));
typedef float f4 __attribute__((ext_vector_type(4)));
typedef unsigned int u4 __attribute__((ext_vector_type(4)));

struct __align__(32) RB { unsigned grow, i1, i2; float p1, p2; unsigned pad[3]; };

// pack 8 floats -> 8 f16 via 4x v_cvt_pkrtz_f32_f16 (1 op per pair)
static __device__ __forceinline__ u4 PK8(f4 x, f4 y) {
    h2 a = __builtin_amdgcn_cvt_pkrtz(x[0], x[1]);
    h2 b = __builtin_amdgcn_cvt_pkrtz(x[2], x[3]);
    h2 c = __builtin_amdgcn_cvt_pkrtz(y[0], y[1]);
    h2 d = __builtin_amdgcn_cvt_pkrtz(y[2], y[3]);
    u4 r;
    r[0] = __builtin_bit_cast(unsigned int, a);
    r[1] = __builtin_bit_cast(unsigned int, b);
    r[2] = __builtin_bit_cast(unsigned int, c);
    r[3] = __builtin_bit_cast(unsigned int, d);
    return r;
}

// Branch-free top-3, packed indices (i1<<16 | i2), absolute exp2 accumulation.
#define TOP3(u_, s_, key_) do {                                             \
    const bool c1_ = (s_) > m1[u_];                                         \
    const bool c2_ = (s_) > m2[u_];                                         \
    const unsigned p_ = ip[u_];                                             \
    const unsigned cnd1_ = ((unsigned)(key_) << 16) | (p_ >> 16);           \
    const unsigned cnd2_ = (p_ & 0xFFFF0000u) | (unsigned)(key_);           \
    ip[u_] = c1_ ? cnd1_ : (c2_ ? cnd2_ : p_);                              \
    m3[u_] = __builtin_amdgcn_fmed3f(s_, m2[u_], m3[u_]);                   \
    m2[u_] = __builtin_amdgcn_fmed3f(s_, m1[u_], m2[u_]);                   \
    m1[u_] = fmaxf(s_, m1[u_]);                                             \
    sm[u_] += __builtin_amdgcn_exp2f(s_);                                   \
} while (0)

// ---- main kernel: 1024 blocks (QB=64), LDS f16 K double-buffered+swizzled,
// ---- pulse-split staging (pkrtz, low VGPR), raw lgkmcnt barrier
// ---- (global stores stay in flight), interleaved NT zeroing.
__global__ __launch_bounds__(256, 3)
void attn_main(const float* __restrict__ Q, const float* __restrict__ K,
               const float* __restrict__ V, float* __restrict__ out,
               int2* __restrict__ recs,
               unsigned* __restrict__ cntA, unsigned* __restrict__ cntB,
               uint2* __restrict__ listA, RB* __restrict__ listB, int capB)
{
    const int P    = blockIdx.x;
    const int x    = P & 7;                 // XCD (round-robin dispatch)
    const int mm   = P >> 3;                // 0..127
    const int b    = (x << 2) + (mm >> 5);  // XCD x owns batches 4x..4x+3
    const int q0   = (mm & 31) << 6;        // 64-row q-tile
    const int tid  = threadIdx.x;
    const int wv   = tid >> 6;
    const int lane = tid & 63;
    const int col  = lane & 15;
    const int kg   = lane >> 4;
    const int wq0  = q0 + (wv << 4);        // wave's 16 q-rows

    const float* kbat = K + (size_t)b * LL * DD;
    float* plane = out + (size_t)BB * LL * DD;
    f4* zb = (f4*)(plane + ((size_t)(b * LL + q0)) * LL);   // 32768 f4 to zero

    __shared__ __align__(16) _Float16 Klds[2][64][128];     // 2 x 16 KB

    // Q A-fragments pre-scaled by SCALE2: lane holds Q[wq0+col][db*32+kg*8+j]
    half8 qa[4];
    {
        const float* qsrc = Q + ((size_t)b * LL + wq0 + col) * DD + (kg << 3);
#pragma unroll
        for (int db = 0; db < 4; ++db) {
            f4 xx = *(const f4*)(qsrc + db * 32);
            f4 yy = *(const f4*)(qsrc + db * 32 + 4);
            half8 h;
            h[0]=(_Float16)(xx[0]*SCALE2); h[1]=(_Float16)(xx[1]*SCALE2);
            h[2]=(_Float16)(xx[2]*SCALE2); h[3]=(_Float16)(xx[3]*SCALE2);
            h[4]=(_Float16)(yy[0]*SCALE2); h[5]=(_Float16)(yy[1]*SCALE2);
            h[6]=(_Float16)(yy[2]*SCALE2); h[7]=(_Float16)(yy[3]*SCALE2);
            qa[db] = h;
        }
    }

    float m1[4], m2[4], m3[4], sm[4];
    unsigned ip[4];
#pragma unroll
    for (int u = 0; u < 4; ++u) { m1[u]=m2[u]=m3[u]=-1e30f; sm[u]=0.f; ip[u]=0u; }

    const int r   = tid >> 2;          // staging row 0..63
    const int q64 = (tid & 3) << 6;    // byte quarter within 256B row
    const int xw  = (r & 7) << 4;      // write-side XOR swizzle
    const int xr  = (col & 7) << 4;    // read-side XOR swizzle
    char* lb0 = (char*)&Klds[0][0][0];
    char* lb1 = (char*)&Klds[1][0][0];
    const float* srow = kbat + (size_t)r * DD + ((tid & 3) << 5);

    // prologue: stage tile 0 -> LDS[0] (pulsed)
    {
        char* wb = lb0 + r * 256;
        f4 a0 = *(const f4*)(srow);      f4 a1 = *(const f4*)(srow + 4);
        f4 a2 = *(const f4*)(srow + 8);  f4 a3 = *(const f4*)(srow + 12);
        *(u4*)(wb + ((q64 +  0) ^ xw)) = PK8(a0, a1);
        *(u4*)(wb + ((q64 + 16) ^ xw)) = PK8(a2, a3);
        a0 = *(const f4*)(srow + 16); a1 = *(const f4*)(srow + 20);
        a2 = *(const f4*)(srow + 24); a3 = *(const f4*)(srow + 28);
        *(u4*)(wb + ((q64 + 32) ^ xw)) = PK8(a0, a1);
        *(u4*)(wb + ((q64 + 48) ^ xw)) = PK8(a2, a3);
    }
    __syncthreads();

    for (int kt = 0; kt < 32; ++kt) {
        char* rbuf = (kt & 1) ? lb1 : lb0;
        char* wbuf = (kt & 1) ? lb0 : lb1;
        const float* snext = srow + (size_t)(kt + 1) * 64 * DD;

        f4 a0, a1, a2, a3;
        if (kt < 31) {   // pulse A issue (hidden under subtiles 0-1)
            a0 = *(const f4*)(snext);      a1 = *(const f4*)(snext + 4);
            a2 = *(const f4*)(snext + 8);  a3 = *(const f4*)(snext + 12);
        }

        // subtiles 0-1
#pragma unroll
        for (int s = 0; s < 2; ++s) {
            const char* rowp = rbuf + ((s << 4) + col) * 256;
            half8 bf0 = *(const half8*)(rowp + ((  0 + (kg << 4)) ^ xr));
            half8 bf1 = *(const half8*)(rowp + (( 64 + (kg << 4)) ^ xr));
            half8 bf2 = *(const half8*)(rowp + ((128 + (kg << 4)) ^ xr));
            half8 bf3 = *(const half8*)(rowp + ((192 + (kg << 4)) ^ xr));
            f4 acc = {0.f, 0.f, 0.f, 0.f};
            acc = __builtin_amdgcn_mfma_f32_16x16x32_f16(qa[0], bf0, acc, 0, 0, 0);
            acc = __builtin_amdgcn_mfma_f32_16x16x32_f16(qa[1], bf1, acc, 0, 0, 0);
            acc = __builtin_amdgcn_mfma_f32_16x16x32_f16(qa[2], bf2, acc, 0, 0, 0);
            acc = __builtin_amdgcn_mfma_f32_16x16x32_f16(qa[3], bf3, acc, 0, 0, 0);
            const int key = (kt << 6) + (s << 4) + col;
#pragma unroll
            for (int j = 0; j < 4; ++j) { float sc = acc[j]; TOP3(j, sc, key); }
        }

        if (kt < 31) {   // write pulse A; issue pulse B (hidden under subtiles 2-3)
            char* wb = wbuf + r * 256;
            *(u4*)(wb + ((q64 +  0) ^ xw)) = PK8(a0, a1);
            *(u4*)(wb + ((q64 + 16) ^ xw)) = PK8(a2, a3);
            a0 = *(const f4*)(snext + 16); a1 = *(const f4*)(snext + 20);
            a2 = *(const f4*)(snext + 24); a3 = *(const f4*)(snext + 28);
        }

        // subtiles 2-3
#pragma unroll
        for (int s = 2; s < 4; ++s) {
            const char* rowp = rbuf + ((s << 4) + col) * 256;
            half8 bf0 = *(const half8*)(rowp + ((  0 + (kg << 4)) ^ xr));
            half8 bf1 = *(const half8*)(rowp + (( 64 + (kg << 4)) ^ xr));
            half8 bf2 = *(const half8*)(rowp + ((128 + (kg << 4)) ^ xr));
            half8 bf3 = *(const half8*)(rowp + ((192 + (kg << 4)) ^ xr));
            f4 acc = {0.f, 0.f, 0.f, 0.f};
            acc = __builtin_amdgcn_mfma_f32_16x16x32_f16(qa[0], bf0, acc, 0, 0, 0);
            acc = __builtin_amdgcn_mfma_f32_16x16x32_f16(qa[1], bf1, acc, 0, 0, 0);
            acc = __builtin_amdgcn_mfma_f32_16x16x32_f16(qa[2], bf2, acc, 0, 0, 0);
            acc = __builtin_amdgcn_mfma_f32_16x16x32_f16(qa[3], bf3, acc, 0, 0, 0);
            const int key = (kt << 6) + (s << 4) + col;
#pragma unroll
            for (int j = 0; j < 4; ++j) { float sc = acc[j]; TOP3(j, sc, key); }
        }

        if (kt < 31) {   // write pulse B
            char* wb = wbuf + r * 256;
            *(u4*)(wb + ((q64 + 32) ^ xw)) = PK8(a0, a1);
            *(u4*)(wb + ((q64 + 48) ^ xw)) = PK8(a2, a3);
        }

        // interleaved zeroing: 4 f4/thread/tile, nontemporal, never drained
        {
            f4 z = {0.f,0.f,0.f,0.f};
            f4* d = zb + (size_t)kt * 1024 + tid;
            __builtin_nontemporal_store(z, d);
            __builtin_nontemporal_store(z, d + 256);
            __builtin_nontemporal_store(z, d + 512);
            __builtin_nontemporal_store(z, d + 768);
        }

        // raw barrier: waits LDS ops only; global stores stay in flight
        asm volatile("s_waitcnt lgkmcnt(0)" ::: "memory");
        __builtin_amdgcn_s_barrier();
    }

    // butterfly merge across the 16 column-lanes (sm merges by simple add)
#pragma unroll
    for (int off = 1; off < 16; off <<= 1) {
#pragma unroll
        for (int u = 0; u < 4; ++u) {
            float om1 = __shfl_xor(m1[u], off);
            float om2 = __shfl_xor(m2[u], off);
            float om3 = __shfl_xor(m3[u], off);
            float osm = __shfl_xor(sm[u], off);
            unsigned oip = __shfl_xor((int)ip[u], off);
            sm[u] += osm;
            if (om1 > m1[u]) {
                float t2; unsigned tp;
                t2=m1[u]; m1[u]=om1; om1=t2;
                t2=m2[u]; m2[u]=om2; om2=t2;
                t2=m3[u]; m3[u]=om3; om3=t2;
                tp=ip[u]; ip[u]=oip; oip=tp;
            }
            if (om1 > m2[u]) { m3[u]=fmaxf(m2[u], om2); m2[u]=om1;
                               ip[u]=(ip[u]&0xFFFF0000u)|(oip>>16); }
            else             { m3[u]=fmaxf(m3[u], om1); }
        }
    }

    if (col == 0) {
#pragma unroll
        for (int u = 0; u < 4; ++u) {
            const int grow = b * LL + wq0 + (kg << 2) + u;
            const unsigned i1u = ip[u] >> 16, i2u = ip[u] & 0xFFFFu;
            float p1 = __builtin_amdgcn_exp2f(m1[u]) / sm[u];
            float g13 = m1[u] - m3[u];
            float g12 = m1[u] - m2[u];
            unsigned flag = 0u;
            if (g13 <= DELTA2) {
                flag = 0x80000000u;
                unsigned slotA = atomicAdd(cntA, 1u);
                if (slotA < CAPA) listA[slotA] = make_uint2((unsigned)grow, i1u);
            } else if (g12 <= DELTA2) {
                flag = 0x80000000u;
                unsigned slotB = atomicAdd(cntB, 1u);
                if (slotB < (unsigned)capB) {
                    RB rb; rb.grow=(unsigned)grow; rb.i1=i1u; rb.i2=i2u;
                    rb.p1=p1; rb.p2=__builtin_amdgcn_exp2f(m2[u])/sm[u];
                    rb.pad[0]=rb.pad[1]=rb.pad[2]=0;
                    listB[slotB] = rb;
                }
            }
            recs[grow] = make_int2((int)(i1u | flag), __float_as_int(p1));
        }
    }

    // output rows: all lanes hold merged state; lane writes 32B of row kg*4+u
#pragma unroll
    for (int u = 0; u < 4; ++u) {
        const int grow = b * LL + wq0 + (kg << 2) + u;
        float p1 = __builtin_amdgcn_exp2f(m1[u]) / sm[u];
        const float* vs = V + ((size_t)b * LL + (ip[u] >> 16)) * DD + (col << 3);
        float* dst = out + (size_t)grow * DD + (col << 3);
        f4 v0 = *(const f4*)(vs);
        f4 v1 = *(const f4*)(vs + 4);
        *(f4*)(dst)     = v0 * p1;
        *(f4*)(dst + 4) = v1 * p1;
    }
}

// ---- merged epilogue: scatter p (skip flagged rows) + fp64 fix-ups.
// ---- All roles touch disjoint rows -> safe in one concurrent kernel.
__global__ __launch_bounds__(256)
void epilogue(const float* __restrict__ Q, const float* __restrict__ K,
              const float* __restrict__ V, float* __restrict__ out,
              const int2* __restrict__ recs,
              const unsigned* __restrict__ cntA, const unsigned* __restrict__ cntB,
              const uint2* __restrict__ listA, const RB* __restrict__ listB, int capB)
{
    __shared__ float  qsh[DD];
    __shared__ double rbuf[256];
    __shared__ int    ibuf[256];
    float* plane = out + (size_t)BB * LL * DD;
    const int bid = blockIdx.x;
    const int tid = threadIdx.x;

    if (bid < 256) {
        // ---- scatter role: place p at argmax for unflagged rows ----
        const int grow = bid * 256 + tid;
        int2 rr = recs[grow];
        if (rr.x >= 0)
            plane[(size_t)grow * LL + rr.x] = __int_as_float(rr.y);
        return;
    }

    if (bid < 320) {
        // ---- fix-full role: fp64 full-row rescan for listA entries ----
        int n = (int)min(*cntA, (unsigned)CAPA);
        for (int e = bid - 256; e < n; e += 64) {
            uint2 en = listA[e];
            int grow = (int)en.x;
            int b = grow >> 11;
            __syncthreads();
            if (tid < DD) qsh[tid] = Q[(size_t)grow * DD + tid];
            __syncthreads();
            double ls[8];
            double best = -1e300; int bidx = 0;
#pragma unroll
            for (int kk = 0; kk < 8; ++kk) {
                int key = (kk << 8) + tid;
                const float* kr = K + ((size_t)(b << 11) + key) * DD;
                double acc = 0.0;
                for (int d = 0; d < DD; ++d) acc += (double)qsh[d] * (double)kr[d];
                acc *= (double)0.08838834764831845;
                ls[kk] = acc;
                if (acc > best) { best = acc; bidx = key; }
            }
            rbuf[tid] = best; ibuf[tid] = bidx;
            __syncthreads();
            for (int s2 = 128; s2 > 0; s2 >>= 1) {
                if (tid < s2 && rbuf[tid + s2] > rbuf[tid]) { rbuf[tid]=rbuf[tid+s2]; ibuf[tid]=ibuf[tid+s2]; }
                __syncthreads();
            }
            double gbest = rbuf[0]; int gidx = ibuf[0];
            __syncthreads();
            double lsum = 0.0;
#pragma unroll
            for (int kk = 0; kk < 8; ++kk) lsum += exp(ls[kk] - gbest);
            rbuf[tid] = lsum;
            __syncthreads();
            for (int s2 = 128; s2 > 0; s2 >>= 1) {
                if (tid < s2) rbuf[tid] += rbuf[tid + s2];
                __syncthreads();
            }
            float p = (float)(1.0 / rbuf[0]);
            if (tid == 0) plane[(size_t)grow * LL + gidx] = p;   // row was left zeroed
            if (tid < DD) out[(size_t)grow * DD + tid] = p * V[((size_t)(b << 11) + gidx) * DD + tid];
            __syncthreads();
        }
        return;
    }

    // ---- fix-pair role: fp64 two-candidate compare, 4 waves/block ----
    {
        int n = (int)min(*cntB, (unsigned)capB);
        const int lane = tid & 63;
        for (int e = (bid - 320) * 4 + (tid >> 6); e < n; e += 256) {
            RB r = listB[e];
            int b = (int)(r.grow >> 11);
            const float* qq = Q + (size_t)r.grow * DD;
            const float* k1 = K + ((size_t)(b << 11) + r.i1) * DD;
            const float* k2 = K + ((size_t)(b << 11) + r.i2) * DD;
            double a1 = 0.0, a2 = 0.0;
            for (int d = lane; d < DD; d += 64) {
                double qd = (double)qq[d];
                a1 += qd * (double)k1[d];
                a2 += qd * (double)k2[d];
            }
#pragma unroll
            for (int off = 32; off > 0; off >>= 1) {
                a1 += __shfl_down(a1, off);
                a2 += __shfl_down(a2, off);
            }
            int sel = (a2 > a1) ? 1 : 0;
            sel = __shfl(sel, 0);
            const unsigned widx = sel ? r.i2 : r.i1;
            const float    wp   = sel ? r.p2 : r.p1;
            if (lane == 0)
                plane[(size_t)r.grow * LL + widx] = wp;   // row was left zeroed
            if (sel) {
                const float* vs = V + ((size_t)(b << 11) + r.i2) * DD;
                float* dst = out + (size_t)r.grow * DD;
                for (int d = lane; d < DD; d += 64) dst[d] = r.p2 * vs[d];
            }
        }
    }
}

extern "C" void kernel_launch(void* const* d_in, const int* in_sizes, int n_in,
                              void* d_out, int out_size, void* d_ws, size_t ws_size,
                              hipStream_t stream)
{
    const float* Q = (const float*)d_in[0];
    const float* K = (const float*)d_in[1];
    const float* V = (const float*)d_in[2];
    float* out = (float*)d_out;

    // ws layout: [0,8) counters | [64, 64+512K) records | listA | listB
    unsigned* cntA = (unsigned*)d_ws;
    unsigned* cntB = cntA + 1;
    int2* recs = (int2*)((char*)d_ws + 64);
    size_t offA = 64 + (size_t)BB * LL * 8;              // 524352
    uint2* listA = (uint2*)((char*)d_ws + offA);
    size_t offB = offA + (size_t)CAPA * 8;               // 557120, 32B-aligned
    RB* listB = (RB*)((char*)d_ws + offB);
    int capB = 0;
    if (ws_size > offB + 32) capB = (int)((ws_size - offB) / 32);
    if (capB > 65536) capB = 65536;

    (void)hipMemsetAsync(d_ws, 0, 8, stream);            // zero both counters
    hipLaunchKernelGGL(attn_main, dim3(1024), dim3(256), 0, stream,
                       Q, K, V, out, recs, cntA, cntB, listA, listB, capB);
    hipLaunchKernelGGL(epilogue, dim3(384), dim3(256), 0, stream,
                       Q, K, V, out, recs, cntA, cntB, listA, listB, capB);
}

// Round 15
// 217.004 us; speedup vs baseline: 1.1595x; 1.1279x over previous
//
#include <hip/hip_runtime.h>

#define BB 32
#define LL 2048
#define DD 128
// Q pre-scale: (1/sqrt(128)) * log2(e)  -> MFMA scores land in log2 units
#define SCALE2 0.12753102f
#define DELTA2 0.0173123f     // 0.012 * log2(e)
#define CAPA 4096

typedef _Float16 half8 __attribute__((ext_vector_type(8)));
typedef __fp16 h2 __attribute__((ext_vector_type(2)));
typedef float f4 __attribute__((ext_vector_type(4)));
typedef unsigned int u4 __attribute__((ext_vector_type(4)));

struct __align__(32) RB { unsigned grow, i1, i2; float p1, p2; unsigned pad[3]; };

// pack 8 floats -> 8 f16 via 4x v_cvt_pkrtz_f32_f16 (1 op per pair)
static __device__ __forceinline__ u4 PK8(f4 x, f4 y) {
    h2 a = __builtin_amdgcn_cvt_pkrtz(x[0], x[1]);
    h2 b = __builtin_amdgcn_cvt_pkrtz(x[2], x[3]);
    h2 c = __builtin_amdgcn_cvt_pkrtz(y[0], y[1]);
    h2 d = __builtin_amdgcn_cvt_pkrtz(y[2], y[3]);
    u4 r;
    r[0] = __builtin_bit_cast(unsigned int, a);
    r[1] = __builtin_bit_cast(unsigned int, b);
    r[2] = __builtin_bit_cast(unsigned int, c);
    r[3] = __builtin_bit_cast(unsigned int, d);
    return r;
}

// Branch-free top-3, packed indices (i1<<16 | i2), absolute exp2 accumulation.
#define TOP3(u_, s_, key_) do {                                             \
    const bool c1_ = (s_) > m1[u_];                                         \
    const bool c2_ = (s_) > m2[u_];                                         \
    const unsigned p_ = ip[u_];                                             \
    const unsigned cnd1_ = ((unsigned)(key_) << 16) | (p_ >> 16);           \
    const unsigned cnd2_ = (p_ & 0xFFFF0000u) | (unsigned)(key_);           \
    ip[u_] = c1_ ? cnd1_ : (c2_ ? cnd2_ : p_);                              \
    m3[u_] = __builtin_amdgcn_fmed3f(s_, m2[u_], m3[u_]);                   \
    m2[u_] = __builtin_amdgcn_fmed3f(s_, m1[u_], m2[u_]);                   \
    m1[u_] = fmaxf(s_, m1[u_]);                                             \
    sm[u_] += __builtin_amdgcn_exp2f(s_);                                   \
} while (0)

// ---- main kernel: 1024 blocks (QB=64), LDS f16 K double-buffered+swizzled,
// ---- pulse-split staging (pkrtz, low VGPR), raw lgkmcnt barrier
// ---- (global stores stay in flight), interleaved NT zeroing.
__global__ __launch_bounds__(256, 2)
void attn_main(const float* __restrict__ Q, const float* __restrict__ K,
               const float* __restrict__ V, float* __restrict__ out,
               int2* __restrict__ recs,
               unsigned* __restrict__ cntA, unsigned* __restrict__ cntB,
               uint2* __restrict__ listA, RB* __restrict__ listB, int capB)
{
    const int P    = blockIdx.x;
    const int x    = P & 7;                 // XCD (round-robin dispatch)
    const int mm   = P >> 3;                // 0..127
    const int b    = (x << 2) + (mm >> 5);  // XCD x owns batches 4x..4x+3
    const int q0   = (mm & 31) << 6;        // 64-row q-tile
    const int tid  = threadIdx.x;
    const int wv   = tid >> 6;
    const int lane = tid & 63;
    const int col  = lane & 15;
    const int kg   = lane >> 4;
    const int wq0  = q0 + (wv << 4);        // wave's 16 q-rows

    const float* kbat = K + (size_t)b * LL * DD;
    float* plane = out + (size_t)BB * LL * DD;
    f4* zb = (f4*)(plane + ((size_t)(b * LL + q0)) * LL);   // 32768 f4 to zero

    __shared__ __align__(16) _Float16 Klds[2][64][128];     // 2 x 16 KB

    // Q A-fragments pre-scaled by SCALE2: lane holds Q[wq0+col][db*32+kg*8+j]
    half8 qa[4];
    {
        const float* qsrc = Q + ((size_t)b * LL + wq0 + col) * DD + (kg << 3);
#pragma unroll
        for (int db = 0; db < 4; ++db) {
            f4 xx = *(const f4*)(qsrc + db * 32);
            f4 yy = *(const f4*)(qsrc + db * 32 + 4);
            half8 h;
            h[0]=(_Float16)(xx[0]*SCALE2); h[1]=(_Float16)(xx[1]*SCALE2);
            h[2]=(_Float16)(xx[2]*SCALE2); h[3]=(_Float16)(xx[3]*SCALE2);
            h[4]=(_Float16)(yy[0]*SCALE2); h[5]=(_Float16)(yy[1]*SCALE2);
            h[6]=(_Float16)(yy[2]*SCALE2); h[7]=(_Float16)(yy[3]*SCALE2);
            qa[db] = h;
        }
    }

    float m1[4], m2[4], m3[4], sm[4];
    unsigned ip[4];
#pragma unroll
    for (int u = 0; u < 4; ++u) { m1[u]=m2[u]=m3[u]=-1e30f; sm[u]=0.f; ip[u]=0u; }

    const int r   = tid >> 2;          // staging row 0..63
    const int q64 = (tid & 3) << 6;    // byte quarter within 256B row
    const int xw  = (r & 7) << 4;      // write-side XOR swizzle
    const int xr  = (col & 7) << 4;    // read-side XOR swizzle
    char* lb0 = (char*)&Klds[0][0][0];
    char* lb1 = (char*)&Klds[1][0][0];
    const float* srow = kbat + (size_t)r * DD + ((tid & 3) << 5);

    // prologue: stage tile 0 -> LDS[0] (pulsed)
    {
        char* wb = lb0 + r * 256;
        f4 a0 = *(const f4*)(srow);      f4 a1 = *(const f4*)(srow + 4);
        f4 a2 = *(const f4*)(srow + 8);  f4 a3 = *(const f4*)(srow + 12);
        *(u4*)(wb + ((q64 +  0) ^ xw)) = PK8(a0, a1);
        *(u4*)(wb + ((q64 + 16) ^ xw)) = PK8(a2, a3);
        a0 = *(const f4*)(srow + 16); a1 = *(const f4*)(srow + 20);
        a2 = *(const f4*)(srow + 24); a3 = *(const f4*)(srow + 28);
        *(u4*)(wb + ((q64 + 32) ^ xw)) = PK8(a0, a1);
        *(u4*)(wb + ((q64 + 48) ^ xw)) = PK8(a2, a3);
    }
    __syncthreads();

    for (int kt = 0; kt < 32; ++kt) {
        char* rbuf = (kt & 1) ? lb1 : lb0;
        char* wbuf = (kt & 1) ? lb0 : lb1;
        const float* snext = srow + (size_t)(kt + 1) * 64 * DD;

        f4 a0, a1, a2, a3;
        if (kt < 31) {   // pulse A issue (hidden under subtiles 0-1)
            a0 = *(const f4*)(snext);      a1 = *(const f4*)(snext + 4);
            a2 = *(const f4*)(snext + 8);  a3 = *(const f4*)(snext + 12);
        }

        // subtiles 0-1
#pragma unroll
        for (int s = 0; s < 2; ++s) {
            const char* rowp = rbuf + ((s << 4) + col) * 256;
            half8 bf0 = *(const half8*)(rowp + ((  0 + (kg << 4)) ^ xr));
            half8 bf1 = *(const half8*)(rowp + (( 64 + (kg << 4)) ^ xr));
            half8 bf2 = *(const half8*)(rowp + ((128 + (kg << 4)) ^ xr));
            half8 bf3 = *(const half8*)(rowp + ((192 + (kg << 4)) ^ xr));
            f4 acc = {0.f, 0.f, 0.f, 0.f};
            acc = __builtin_amdgcn_mfma_f32_16x16x32_f16(qa[0], bf0, acc, 0, 0, 0);
            acc = __builtin_amdgcn_mfma_f32_16x16x32_f16(qa[1], bf1, acc, 0, 0, 0);
            acc = __builtin_amdgcn_mfma_f32_16x16x32_f16(qa[2], bf2, acc, 0, 0, 0);
            acc = __builtin_amdgcn_mfma_f32_16x16x32_f16(qa[3], bf3, acc, 0, 0, 0);
            const int key = (kt << 6) + (s << 4) + col;
#pragma unroll
            for (int j = 0; j < 4; ++j) { float sc = acc[j]; TOP3(j, sc, key); }
        }

        if (kt < 31) {   // write pulse A; issue pulse B (hidden under subtiles 2-3)
            char* wb = wbuf + r * 256;
            *(u4*)(wb + ((q64 +  0) ^ xw)) = PK8(a0, a1);
            *(u4*)(wb + ((q64 + 16) ^ xw)) = PK8(a2, a3);
            a0 = *(const f4*)(snext + 16); a1 = *(const f4*)(snext + 20);
            a2 = *(const f4*)(snext + 24); a3 = *(const f4*)(snext + 28);
        }

        // subtiles 2-3
#pragma unroll
        for (int s = 2; s < 4; ++s) {
            const char* rowp = rbuf + ((s << 4) + col) * 256;
            half8 bf0 = *(const half8*)(rowp + ((  0 + (kg << 4)) ^ xr));
            half8 bf1 = *(const half8*)(rowp + (( 64 + (kg << 4)) ^ xr));
            half8 bf2 = *(const half8*)(rowp + ((128 + (kg << 4)) ^ xr));
            half8 bf3 = *(const half8*)(rowp + ((192 + (kg << 4)) ^ xr));
            f4 acc = {0.f, 0.f, 0.f, 0.f};
            acc = __builtin_amdgcn_mfma_f32_16x16x32_f16(qa[0], bf0, acc, 0, 0, 0);
            acc = __builtin_amdgcn_mfma_f32_16x16x32_f16(qa[1], bf1, acc, 0, 0, 0);
            acc = __builtin_amdgcn_mfma_f32_16x16x32_f16(qa[2], bf2, acc, 0, 0, 0);
            acc = __builtin_amdgcn_mfma_f32_16x16x32_f16(qa[3], bf3, acc, 0, 0, 0);
            const int key = (kt << 6) + (s << 4) + col;
#pragma unroll
            for (int j = 0; j < 4; ++j) { float sc = acc[j]; TOP3(j, sc, key); }
        }

        if (kt < 31) {   // write pulse B
            char* wb = wbuf + r * 256;
            *(u4*)(wb + ((q64 + 32) ^ xw)) = PK8(a0, a1);
            *(u4*)(wb + ((q64 + 48) ^ xw)) = PK8(a2, a3);
        }

        // interleaved zeroing: 4 f4/thread/tile, nontemporal, never drained
        {
            f4 z = {0.f,0.f,0.f,0.f};
            f4* d = zb + (size_t)kt * 1024 + tid;
            __builtin_nontemporal_store(z, d);
            __builtin_nontemporal_store(z, d + 256);
            __builtin_nontemporal_store(z, d + 512);
            __builtin_nontemporal_store(z, d + 768);
        }

        // raw barrier: waits LDS ops only; global stores stay in flight
        asm volatile("s_waitcnt lgkmcnt(0)" ::: "memory");
        __builtin_amdgcn_s_barrier();
    }

    // butterfly merge across the 16 column-lanes (sm merges by simple add)
#pragma unroll
    for (int off = 1; off < 16; off <<= 1) {
#pragma unroll
        for (int u = 0; u < 4; ++u) {
            float om1 = __shfl_xor(m1[u], off);
            float om2 = __shfl_xor(m2[u], off);
            float om3 = __shfl_xor(m3[u], off);
            float osm = __shfl_xor(sm[u], off);
            unsigned oip = __shfl_xor((int)ip[u], off);
            sm[u] += osm;
            if (om1 > m1[u]) {
                float t2; unsigned tp;
                t2=m1[u]; m1[u]=om1; om1=t2;
                t2=m2[u]; m2[u]=om2; om2=t2;
                t2=m3[u]; m3[u]=om3; om3=t2;
                tp=ip[u]; ip[u]=oip; oip=tp;
            }
            if (om1 > m2[u]) { m3[u]=fmaxf(m2[u], om2); m2[u]=om1;
                               ip[u]=(ip[u]&0xFFFF0000u)|(oip>>16); }
            else             { m3[u]=fmaxf(m3[u], om1); }
        }
    }

    if (col == 0) {
#pragma unroll
        for (int u = 0; u < 4; ++u) {
            const int grow = b * LL + wq0 + (kg << 2) + u;
            const unsigned i1u = ip[u] >> 16, i2u = ip[u] & 0xFFFFu;
            float p1 = __builtin_amdgcn_exp2f(m1[u]) / sm[u];
            float g13 = m1[u] - m3[u];
            float g12 = m1[u] - m2[u];
            unsigned flag = 0u;
            if (g13 <= DELTA2) {
                flag = 0x80000000u;
                unsigned slotA = atomicAdd(cntA, 1u);
                if (slotA < CAPA) listA[slotA] = make_uint2((unsigned)grow, i1u);
            } else if (g12 <= DELTA2) {
                flag = 0x80000000u;
                unsigned slotB = atomicAdd(cntB, 1u);
                if (slotB < (unsigned)capB) {
                    RB rb; rb.grow=(unsigned)grow; rb.i1=i1u; rb.i2=i2u;
                    rb.p1=p1; rb.p2=__builtin_amdgcn_exp2f(m2[u])/sm[u];
                    rb.pad[0]=rb.pad[1]=rb.pad[2]=0;
                    listB[slotB] = rb;
                }
            }
            recs[grow] = make_int2((int)(i1u | flag), __float_as_int(p1));
        }
    }

    // output rows: all lanes hold merged state; lane writes 32B of row kg*4+u
#pragma unroll
    for (int u = 0; u < 4; ++u) {
        const int grow = b * LL + wq0 + (kg << 2) + u;
        float p1 = __builtin_amdgcn_exp2f(m1[u]) / sm[u];
        const float* vs = V + ((size_t)b * LL + (ip[u] >> 16)) * DD + (col << 3);
        float* dst = out + (size_t)grow * DD + (col << 3);
        f4 v0 = *(const f4*)(vs);
        f4 v1 = *(const f4*)(vs + 4);
        *(f4*)(dst)     = v0 * p1;
        *(f4*)(dst + 4) = v1 * p1;
    }
}

// ---- scatter_p: after zeroing completes, place p at each row's argmax
// ---- (skips flagged ambiguous rows; fix-ups own those).
__global__ __launch_bounds__(256)
void scatter_p(float* __restrict__ out, const int2* __restrict__ recs)
{
    const int grow = blockIdx.x * 256 + threadIdx.x;     // 0..65535
    int2 r = recs[grow];
    if (r.x >= 0)
        out[(size_t)BB * LL * DD + (size_t)grow * LL + r.x] = __int_as_float(r.y);
}

// ---------------- fix-up B: two-candidate fp64 compare ----------------
__global__ __launch_bounds__(64)
void fix_pair(const float* __restrict__ Q, const float* __restrict__ K,
              const float* __restrict__ V, float* __restrict__ out,
              const unsigned* __restrict__ cntB, const RB* __restrict__ listB, int capB)
{
    int n = (int)min(*cntB, (unsigned)capB);
    float* plane = out + (size_t)BB * LL * DD;
    int lane = threadIdx.x;
    for (int e = blockIdx.x; e < n; e += gridDim.x) {
        RB r = listB[e];
        int b = (int)(r.grow >> 11);
        const float* q  = Q + (size_t)r.grow * DD;
        const float* k1 = K + ((size_t)(b << 11) + r.i1) * DD;
        const float* k2 = K + ((size_t)(b << 11) + r.i2) * DD;
        double a1 = 0.0, a2 = 0.0;
        for (int d = lane; d < DD; d += 64) {
            double qd = (double)q[d];
            a1 += qd * (double)k1[d];
            a2 += qd * (double)k2[d];
        }
#pragma unroll
        for (int off = 32; off > 0; off >>= 1) {
            a1 += __shfl_down(a1, off);
            a2 += __shfl_down(a2, off);
        }
        int sel = (a2 > a1) ? 1 : 0;
        sel = __shfl(sel, 0);
        const unsigned widx = sel ? r.i2 : r.i1;
        const float    wp   = sel ? r.p2 : r.p1;
        if (lane == 0)
            plane[(size_t)r.grow * LL + widx] = wp;   // row was left zeroed
        if (sel) {
            const float* vs = V + ((size_t)(b << 11) + r.i2) * DD;
            float* dst = out + (size_t)r.grow * DD;
            for (int d = lane; d < DD; d += 64) dst[d] = r.p2 * vs[d];
        }
    }
}

// ---------------- fix-up A: full fp64 row rescan ----------------
__global__ __launch_bounds__(256)
void fix_full(const float* __restrict__ Q, const float* __restrict__ K,
              const float* __restrict__ V, float* __restrict__ out,
              const unsigned* __restrict__ cntA, const uint2* __restrict__ listA)
{
    __shared__ float  qsh[DD];
    __shared__ double rbuf[256];
    __shared__ int    ibuf[256];
    int n = (int)min(*cntA, (unsigned)CAPA);
    float* plane = out + (size_t)BB * LL * DD;
    int tid = threadIdx.x;
    for (int e = blockIdx.x; e < n; e += gridDim.x) {
        uint2 en = listA[e];
        int grow = (int)en.x;
        int b = grow >> 11;
        __syncthreads();
        if (tid < DD) qsh[tid] = Q[(size_t)grow * DD + tid];
        __syncthreads();
        double ls[8];
        double best = -1e300; int bidx = 0;
#pragma unroll
        for (int kk = 0; kk < 8; ++kk) {
            int key = (kk << 8) + tid;
            const float* kr = K + ((size_t)(b << 11) + key) * DD;
            double acc = 0.0;
            for (int d = 0; d < DD; ++d) acc += (double)qsh[d] * (double)kr[d];
            acc *= (double)0.08838834764831845;
            ls[kk] = acc;
            if (acc > best) { best = acc; bidx = key; }
        }
        rbuf[tid] = best; ibuf[tid] = bidx;
        __syncthreads();
        for (int s2 = 128; s2 > 0; s2 >>= 1) {
            if (tid < s2 && rbuf[tid + s2] > rbuf[tid]) { rbuf[tid]=rbuf[tid+s2]; ibuf[tid]=ibuf[tid+s2]; }
            __syncthreads();
        }
        double gbest = rbuf[0]; int gidx = ibuf[0];
        __syncthreads();
        double lsum = 0.0;
#pragma unroll
        for (int kk = 0; kk < 8; ++kk) lsum += exp(ls[kk] - gbest);
        rbuf[tid] = lsum;
        __syncthreads();
        for (int s2 = 128; s2 > 0; s2 >>= 1) {
            if (tid < s2) rbuf[tid] += rbuf[tid + s2];
            __syncthreads();
        }
        float p = (float)(1.0 / rbuf[0]);
        if (tid == 0) plane[(size_t)grow * LL + gidx] = p;   // row was left zeroed
        if (tid < DD) out[(size_t)grow * DD + tid] = p * V[((size_t)(b << 11) + gidx) * DD + tid];
        __syncthreads();
    }
}

extern "C" void kernel_launch(void* const* d_in, const int* in_sizes, int n_in,
                              void* d_out, int out_size, void* d_ws, size_t ws_size,
                              hipStream_t stream)
{
    const float* Q = (const float*)d_in[0];
    const float* K = (const float*)d_in[1];
    const float* V = (const float*)d_in[2];
    float* out = (float*)d_out;

    // ws layout: [0,8) counters | [64, 64+512K) records | listA | listB
    unsigned* cntA = (unsigned*)d_ws;
    unsigned* cntB = cntA + 1;
    int2* recs = (int2*)((char*)d_ws + 64);
    size_t offA = 64 + (size_t)BB * LL * 8;              // 524352
    uint2* listA = (uint2*)((char*)d_ws + offA);
    size_t offB = offA + (size_t)CAPA * 8;               // 557120, 32B-aligned
    RB* listB = (RB*)((char*)d_ws + offB);
    int capB = 0;
    if (ws_size > offB + 32) capB = (int)((ws_size - offB) / 32);
    if (capB > 65536) capB = 65536;

    (void)hipMemsetAsync(d_ws, 0, 8, stream);            // zero both counters
    hipLaunchKernelGGL(attn_main, dim3(1024), dim3(256), 0, stream,
                       Q, K, V, out, recs, cntA, cntB, listA, listB, capB);
    hipLaunchKernelGGL(scatter_p, dim3(256), dim3(256), 0, stream, out, recs);
    hipLaunchKernelGGL(fix_full, dim3(256), dim3(256), 0, stream, Q, K, V, out, cntA, listA);
    hipLaunchKernelGGL(fix_pair, dim3(2048), dim3(64), 0, stream, Q, K, V, out, cntB, listB, capB);
}